// Round 1
// baseline (3142.522 us; speedup 1.0000x reference)
//
#include <hip/hip_runtime.h>

// PACE DAG-transformer encoder, MI355X bf16-MFMA implementation.
// B=1024, N=32 nodes, NHID=512, NHEAD=8, NL=6, HID=16384, NZ=64.

typedef unsigned short u16;
typedef unsigned int u32;
typedef __attribute__((ext_vector_type(8))) short bf16x8;
typedef __attribute__((ext_vector_type(4))) float f32x4;

#define NB 1024
#define MAXN 32
#define NHID 512
#define NHEAD 8
#define DH 64
#define NLAY 6
#define MTOT (NB * MAXN)   // 32768 rows
#define ATT_SCALE 0.125f
#define LN_EPS 1e-5f

__device__ __forceinline__ float bf2f(u16 h) { return __uint_as_float(((u32)h) << 16); }
__device__ __forceinline__ u16 f2bf(float f) {
  u32 u = __float_as_uint(f);
  return (u16)((u + 0x7fffu + ((u >> 16) & 1u)) >> 16);
}

__device__ __forceinline__ void gload16(const void* g, void* l) {
  __builtin_amdgcn_global_load_lds((const __attribute__((address_space(1))) void*)g,
                                   (__attribute__((address_space(3))) void*)l, 16, 0, 0);
}

// ---------------------------------------------------------------------------
// DAG reachability mask: per (b,q) a 32-bit "allowed key" mask.
// reach = transitive closure of strictly-upper adj; allowed[q] bit k =
// reach[k][q] | (k==q).
__global__ __launch_bounds__(256) void mask_k(const int* __restrict__ adj, u32* __restrict__ mask) {
  __shared__ u32 r[8][32];
  int tid = threadIdx.x;
  int g = tid >> 5, i = tid & 31;
  int b = blockIdx.x * 8 + g;
  const int* ab = adj + ((long)b * 32 + i) * 32;
  u32 m = 0;
  for (int j = i + 1; j < 32; ++j)
    if (ab[j]) m |= (1u << j);
  r[g][i] = m;
  __syncthreads();
  for (int it = 0; it < 5; ++it) {   // log-depth squaring: paths up to 2^5
    u32 cur = r[g][i];
    u32 acc = cur;
    #pragma unroll
    for (int j = 0; j < 32; ++j)
      if ((cur >> j) & 1u) acc |= r[g][j];
    __syncthreads();
    r[g][i] = acc;
    __syncthreads();
  }
  u32 am = 1u << i;
  #pragma unroll
  for (int k = 0; k < 32; ++k) am |= ((r[g][k] >> i) & 1u) << k;
  mask[b * 32 + i] = am;
}

// ---------------------------------------------------------------------------
// Embedding: x[:, :256] = relu(Wnode[type]+bnode); x[:, 256:] = Wpos[n]+bpos.
__global__ __launch_bounds__(256) void embed_k(const int* __restrict__ types,
    const float* __restrict__ Wpos, const float* __restrict__ bpos,
    const float* __restrict__ Wnode, const float* __restrict__ bnode,
    float* __restrict__ x, u16* __restrict__ xb) {
  int i = blockIdx.x * 256 + threadIdx.x;   // over 32768*128 float4 chunks
  int row = i >> 7, c = (i & 127) * 4;
  int b = row >> 5, n = row & 31;
  float v[4];
  if (c < 256) {
    int tp = types[b * 32 + n];
    const float* w = &Wnode[tp * 256 + c];
    #pragma unroll
    for (int j = 0; j < 4; ++j) v[j] = fmaxf(w[j] + bnode[c + j], 0.f);
  } else {
    int cc = c - 256;
    const float* w = &Wpos[n * 256 + cc];
    #pragma unroll
    for (int j = 0; j < 4; ++j) v[j] = w[j] + bpos[cc + j];
  }
  long o = (long)row * NHID + c;
  *(float4*)&x[o] = make_float4(v[0], v[1], v[2], v[3]);
  ushort4 h; h.x = f2bf(v[0]); h.y = f2bf(v[1]); h.z = f2bf(v[2]); h.w = f2bf(v[3]);
  *(ushort4*)&xb[o] = h;
}

// ---------------------------------------------------------------------------
// Weight transpose + f32->bf16: W[l][k][n] -> Wt[l][n_off+n][k]
__global__ __launch_bounds__(256) void tconv_k(const float* __restrict__ W,
    u16* __restrict__ Wt, int n_off, int n_total) {
  __shared__ float tile[32][33];
  int l = blockIdx.z;
  int k0 = blockIdx.x * 32, n0 = blockIdx.y * 32;
  int tx = threadIdx.x & 31, ty = threadIdx.x >> 5;   // ty 0..7
  const float* src = W + (size_t)l * NHID * NHID;
  #pragma unroll
  for (int i = 0; i < 4; ++i)
    tile[ty + 8 * i][tx] = src[(size_t)(k0 + ty + 8 * i) * NHID + n0 + tx];
  __syncthreads();
  u16* dst = Wt + (size_t)l * n_total * NHID;
  #pragma unroll
  for (int i = 0; i < 4; ++i)
    dst[(size_t)(n_off + n0 + ty + 8 * i) * NHID + k0 + tx] = f2bf(tile[tx][ty + 8 * i]);
}

// ---------------------------------------------------------------------------
// bf16 MFMA GEMM, m97 structure: C[M][N] = A[M][K] * Bt[N][K]^T (+bias).
// 128x128 tile, BK=32, 256 threads (4 waves, 2x2 of 64x64), global_load_lds.
// EPI: 0 = f32 out + bias; 1 = bf16 out + bias; 2 = bf16 out + bias + relu
template <int EPI>
__global__ __launch_bounds__(256, 2) void gemm_bt(
    const u16* __restrict__ A, const u16* __restrict__ Bt,
    const float* __restrict__ bias0, const float* __restrict__ bias1,
    const float* __restrict__ bias2, void* __restrict__ Cout, int N, int K) {
  __shared__ u16 As[128 * 32];
  __shared__ u16 Bs[128 * 32];
  const int tid = threadIdx.x;
  const int wave = tid >> 6, lane = tid & 63;
  const long m0 = (long)blockIdx.y * 128;
  const int n0 = blockIdx.x * 128;
  const int wr = wave >> 1, wc = wave & 1;
  const int srow = lane >> 2;          // row within 16-row chunk
  const int skof = (lane & 3) * 8;     // k element offset within chunk row
  const int fr = lane & 15;            // fragment row/col
  const int kq = lane >> 4;            // k quadrant (8 elems each)
  f32x4 acc[4][4] = {};

  for (int k0 = 0; k0 < K; k0 += 32) {
    #pragma unroll
    for (int i = 0; i < 2; ++i) {
      int c = 2 * wave + i;            // 16-row chunk id (0..7)
      const u16* ga = A + (m0 + 16 * c + srow) * (long)K + k0 + skof;
      gload16(ga, &As[c * 512]);
      const u16* gb = Bt + (long)(n0 + 16 * c + srow) * K + k0 + skof;
      gload16(gb, &Bs[c * 512]);
    }
    __syncthreads();                   // waits vmcnt(0): staged data ready
    bf16x8 af[4], bfr[4];
    #pragma unroll
    for (int mi = 0; mi < 4; ++mi)
      af[mi] = *(const bf16x8*)&As[(wr * 64 + mi * 16 + fr) * 32 + kq * 8];
    #pragma unroll
    for (int ni = 0; ni < 4; ++ni)
      bfr[ni] = *(const bf16x8*)&Bs[(wc * 64 + ni * 16 + fr) * 32 + kq * 8];
    #pragma unroll
    for (int mi = 0; mi < 4; ++mi)
      #pragma unroll
      for (int ni = 0; ni < 4; ++ni)
        acc[mi][ni] = __builtin_amdgcn_mfma_f32_16x16x32_bf16(af[mi], bfr[ni], acc[mi][ni], 0, 0, 0);
    __syncthreads();                   // protect LDS before next stage
  }

  #pragma unroll
  for (int ni = 0; ni < 4; ++ni) {
    int n = n0 + wc * 64 + ni * 16 + fr;
    const float* bp = (n < 512) ? bias0 : ((n < 1024) ? bias1 : bias2);
    float bias = bp[n & 511];
    #pragma unroll
    for (int mi = 0; mi < 4; ++mi) {
      long r = m0 + wr * 64 + mi * 16 + kq * 4;   // C/D: row=(lane>>4)*4+j
      #pragma unroll
      for (int j = 0; j < 4; ++j) {
        float v = acc[mi][ni][j] + bias;
        if (EPI == 2) v = fmaxf(v, 0.f);
        if (EPI == 0) ((float*)Cout)[(r + j) * (long)N + n] = v;
        else          ((u16*)Cout)[(r + j) * (long)N + n] = f2bf(v);
      }
    }
  }
}

// ---------------------------------------------------------------------------
// Masked attention, one block per (b, head), 64 threads.
__global__ __launch_bounds__(64) void attn_k(const u16* __restrict__ qkv,
    const u32* __restrict__ mask, u16* __restrict__ o) {
  __shared__ u16 ks_[32 * 64], vs_[32 * 64];
  __shared__ float as_[32][33];
  int tid = threadIdx.x;
  int b = blockIdx.x >> 3, h = blockIdx.x & 7;
  const u16* base = qkv + (long)b * 32 * 1536;
  {
    int r = tid >> 1, cof = (tid & 1) * 32;
    const u16* kg = base + (long)r * 1536 + 512 + h * 64 + cof;
    const u16* vg = base + (long)r * 1536 + 1024 + h * 64 + cof;
    #pragma unroll
    for (int i = 0; i < 4; ++i) {
      *(uint4*)&ks_[r * 64 + cof + i * 8] = *(const uint4*)&kg[i * 8];
      *(uint4*)&vs_[r * 64 + cof + i * 8] = *(const uint4*)&vg[i * 8];
    }
  }
  __syncthreads();
  if (tid < 32) {
    int r = tid;
    float qr[64];
    const u16* qg = base + (long)r * 1536 + h * 64;
    #pragma unroll
    for (int d = 0; d < 64; ++d) qr[d] = bf2f(qg[d]);
    u32 mk = mask[b * 32 + r];
    float sc[32];
    float mx = -1e30f;
    #pragma unroll
    for (int j = 0; j < 32; ++j) {
      float s = -1e30f;
      if ((mk >> j) & 1u) {
        float acc = 0.f;
        #pragma unroll
        for (int d = 0; d < 64; ++d) acc += qr[d] * bf2f(ks_[j * 64 + d]);
        s = acc * ATT_SCALE;
      }
      sc[j] = s;
      mx = fmaxf(mx, s);
    }
    float sum = 0.f;
    #pragma unroll
    for (int j = 0; j < 32; ++j) {
      float e = ((mk >> j) & 1u) ? __expf(sc[j] - mx) : 0.f;
      sc[j] = e;
      sum += e;
    }
    float inv = 1.f / sum;
    #pragma unroll
    for (int j = 0; j < 32; ++j) as_[r][j] = sc[j] * inv;
  }
  __syncthreads();
  {
    int r = tid & 31, d0 = (tid >> 5) * 32;
    u16* og = o + ((long)b * 32 + r) * NHID + h * 64 + d0;
    #pragma unroll
    for (int d = 0; d < 32; ++d) {
      float acc = 0.f;
      #pragma unroll
      for (int j = 0; j < 32; ++j) acc += as_[r][j] * bf2f(vs_[j * 64 + d0 + d]);
      og[d] = f2bf(acc);
    }
  }
}

// ---------------------------------------------------------------------------
// Residual + LayerNorm: x = LN(x + t)*g + b, writes f32 master + bf16 copy.
// 2 rows per block (128 threads/row, float4/thread).
__global__ __launch_bounds__(256) void ln_k(float* xio, const float* __restrict__ t,
    const float* __restrict__ g, const float* __restrict__ b, u16* __restrict__ xb) {
  __shared__ float ps[4], psq[4];
  int tid = threadIdx.x;
  int half = tid >> 7, lt = tid & 127;
  long row = (long)blockIdx.x * 2 + half;
  int c = lt * 4;
  long o = row * NHID + c;
  float4 xv = *(const float4*)&xio[o];
  const float4 tv = *(const float4*)&t[o];
  float y[4] = {xv.x + tv.x, xv.y + tv.y, xv.z + tv.z, xv.w + tv.w};
  float s = y[0] + y[1] + y[2] + y[3];
  float sq = y[0] * y[0] + y[1] * y[1] + y[2] * y[2] + y[3] * y[3];
  #pragma unroll
  for (int off = 32; off; off >>= 1) {
    s += __shfl_down(s, off);
    sq += __shfl_down(sq, off);
  }
  int wave = tid >> 6;
  if ((tid & 63) == 0) { ps[wave] = s; psq[wave] = sq; }
  __syncthreads();
  int w0 = half * 2;
  float S = ps[w0] + ps[w0 + 1], SQ = psq[w0] + psq[w0 + 1];
  float mean = S * (1.f / 512.f);
  float var = SQ * (1.f / 512.f) - mean * mean;
  float inv = rsqrtf(var + LN_EPS);
  float out[4];
  #pragma unroll
  for (int j = 0; j < 4; ++j) out[j] = (y[j] - mean) * inv * g[c + j] + b[c + j];
  *(float4*)&xio[o] = make_float4(out[0], out[1], out[2], out[3]);
  ushort4 hv; hv.x = f2bf(out[0]); hv.y = f2bf(out[1]); hv.z = f2bf(out[2]); hv.w = f2bf(out[3]);
  *(ushort4*)&xb[o] = hv;
}

// ---------------------------------------------------------------------------
// Final FC partials: grid (64 batch-tiles of 16, 4 k-splits).
// thread = (z 0..63, sel 0..1 -> W1/W2, kg 0..1). part[ks][b][sel*64+z].
__global__ __launch_bounds__(256) void fc_part_k(const float* __restrict__ mem,
    const float* __restrict__ W1, const float* __restrict__ W2,
    float* __restrict__ part) {
  __shared__ float ms[16][512];
  __shared__ float red[128][16];
  int tid = threadIdx.x;
  int z = tid & 63, sel = (tid >> 6) & 1, kg = tid >> 7;
  int b0 = blockIdx.x * 16;
  int ks = blockIdx.y;
  const float* Wp = sel ? W2 : W1;
  float acc[16];
  #pragma unroll
  for (int i = 0; i < 16; ++i) acc[i] = 0.f;
  for (int kt = 0; kt < 8; ++kt) {
    int kbase = ks * 4096 + kt * 512;
    __syncthreads();
    #pragma unroll
    for (int i = 0; i < 8; ++i) {
      int off = i * 1024 + tid * 4;
      int rr = off >> 9, cc = off & 511;
      *(float4*)&ms[rr][cc] = *(const float4*)&mem[(long)(b0 + rr) * 16384 + kbase + cc];
    }
    __syncthreads();
    for (int hl = kg; hl < 512; hl += 2) {
      float w = Wp[(long)(kbase + hl) * 64 + z];
      #pragma unroll
      for (int i = 0; i < 16; ++i) acc[i] += ms[i][hl] * w;
    }
  }
  __syncthreads();
  if (kg == 1) {
    #pragma unroll
    for (int i = 0; i < 16; ++i) red[sel * 64 + z][i] = acc[i];
  }
  __syncthreads();
  if (kg == 0) {
    #pragma unroll
    for (int i = 0; i < 16; ++i)
      part[((long)ks * 1024 + b0 + i) * 128 + sel * 64 + z] = acc[i] + red[sel * 64 + z][i];
  }
}

__global__ __launch_bounds__(256) void fc_red_k(const float* __restrict__ part,
    const float* __restrict__ bfc1, const float* __restrict__ bfc2,
    float* __restrict__ out) {
  int idx = blockIdx.x * 256 + threadIdx.x;   // 0..131071
  int sel = idx >> 16;
  int rem = idx & 65535;
  int b = rem >> 6, z = rem & 63;
  float v = sel ? bfc2[z] : bfc1[z];
  #pragma unroll
  for (int ks = 0; ks < 4; ++ks)
    v += part[((long)ks * 1024 + b) * 128 + sel * 64 + z];
  out[idx] = v;
}

// ---------------------------------------------------------------------------
extern "C" void kernel_launch(void* const* d_in, const int* in_sizes, int n_in,
                              void* d_out, int out_size, void* d_ws, size_t ws_size,
                              hipStream_t stream) {
  const int* node_types = (const int*)d_in[0];
  const int* adj_bits = (const int*)d_in[1];
  const float* Wpos = (const float*)d_in[2];
  const float* bpos = (const float*)d_in[3];
  const float* Wnode = (const float*)d_in[4];
  const float* bnode = (const float*)d_in[5];
  const float* eWq = (const float*)d_in[6];
  const float* eWk = (const float*)d_in[7];
  const float* eWv = (const float*)d_in[8];
  const float* eWo = (const float*)d_in[9];
  const float* eW1 = (const float*)d_in[10];
  const float* eW2 = (const float*)d_in[11];
  const float* ebq = (const float*)d_in[12];
  const float* ebk = (const float*)d_in[13];
  const float* ebv = (const float*)d_in[14];
  const float* ebo = (const float*)d_in[15];
  const float* eb1 = (const float*)d_in[16];
  const float* eb2 = (const float*)d_in[17];
  const float* ln1g = (const float*)d_in[18];
  const float* ln1b = (const float*)d_in[19];
  const float* ln2g = (const float*)d_in[20];
  const float* ln2b = (const float*)d_in[21];
  const float* Wfc1 = (const float*)d_in[22];
  const float* bfc1 = (const float*)d_in[23];
  const float* Wfc2 = (const float*)d_in[24];
  const float* bfc2 = (const float*)d_in[25];

  char* ws = (char*)d_ws;
  size_t off = 0;
  auto carve = [&](size_t bytes) {
    void* p = ws + off;
    off += (bytes + 255) & ~(size_t)255;
    return p;
  };
  u16* Wqkv_t = (u16*)carve((size_t)NLAY * 1536 * 512 * 2);
  u16* Wo_t = (u16*)carve((size_t)NLAY * 512 * 512 * 2);
  u16* W1_t = (u16*)carve((size_t)NLAY * 512 * 512 * 2);
  u16* W2_t = (u16*)carve((size_t)NLAY * 512 * 512 * 2);
  float* xf = (float*)carve((size_t)MTOT * NHID * 4);
  u16* xb = (u16*)carve((size_t)MTOT * NHID * 2);
  u16* qkv = (u16*)carve((size_t)MTOT * 1536 * 2);   // also reused as f32 tmp
  u16* obuf = (u16*)carve((size_t)MTOT * NHID * 2);  // also reused as h
  u32* maskb = (u32*)carve((size_t)NB * MAXN * 4);
  float* part = (float*)carve((size_t)4 * NB * 128 * 4);
  float* tmp = (float*)qkv;
  u16* hbuf = obuf;

  // --- prep ---
  mask_k<<<NB / 8, 256, 0, stream>>>(adj_bits, maskb);
  embed_k<<<(MTOT * 128) / 256, 256, 0, stream>>>(node_types, Wpos, bpos, Wnode, bnode, xf, xb);
  dim3 tg(16, 16, NLAY);
  tconv_k<<<tg, 256, 0, stream>>>(eWq, Wqkv_t, 0, 1536);
  tconv_k<<<tg, 256, 0, stream>>>(eWk, Wqkv_t, 512, 1536);
  tconv_k<<<tg, 256, 0, stream>>>(eWv, Wqkv_t, 1024, 1536);
  tconv_k<<<tg, 256, 0, stream>>>(eWo, Wo_t, 0, 512);
  tconv_k<<<tg, 256, 0, stream>>>(eW1, W1_t, 0, 512);
  tconv_k<<<tg, 256, 0, stream>>>(eW2, W2_t, 0, 512);

  // --- encoder layers ---
  for (int l = 0; l < NLAY; ++l) {
    size_t lw = (size_t)l * 512 * 512;
    gemm_bt<1><<<dim3(12, MTOT / 128), 256, 0, stream>>>(
        xb, Wqkv_t + (size_t)l * 1536 * 512,
        ebq + l * 512, ebk + l * 512, ebv + l * 512, qkv, 1536, 512);
    attn_k<<<NB * NHEAD, 64, 0, stream>>>(qkv, maskb, obuf);
    gemm_bt<0><<<dim3(4, MTOT / 128), 256, 0, stream>>>(
        obuf, Wo_t + lw, ebo + l * 512, ebo + l * 512, ebo + l * 512, tmp, 512, 512);
    ln_k<<<MTOT / 2, 256, 0, stream>>>(xf, tmp, ln1g + l * 512, ln1b + l * 512, xb);
    gemm_bt<2><<<dim3(4, MTOT / 128), 256, 0, stream>>>(
        xb, W1_t + lw, eb1 + l * 512, eb1 + l * 512, eb1 + l * 512, hbuf, 512, 512);
    gemm_bt<0><<<dim3(4, MTOT / 128), 256, 0, stream>>>(
        hbuf, W2_t + lw, eb2 + l * 512, eb2 + l * 512, eb2 + l * 512, tmp, 512, 512);
    ln_k<<<MTOT / 2, 256, 0, stream>>>(xf, tmp, ln2g + l * 512, ln2b + l * 512, xb);
  }

  // --- final FC (deterministic k-split partials + reduce) ---
  fc_part_k<<<dim3(64, 4), 256, 0, stream>>>(xf, Wfc1, Wfc2, part);
  fc_red_k<<<512, 256, 0, stream>>>(part, bfc1, bfc2, (float*)d_out);
}

// Round 2
// 1566.541 us; speedup vs baseline: 2.0060x; 2.0060x over previous
//
#include <hip/hip_runtime.h>

// PACE DAG-transformer encoder, MI355X bf16-MFMA implementation. Round 2:
// MFMA attention (1 wave per (b,head)), MFMA final FC, bf16 LN input path.

typedef unsigned short u16;
typedef unsigned int u32;
typedef __attribute__((ext_vector_type(8))) short bf16x8;
typedef __attribute__((ext_vector_type(4))) float f32x4;

#define NB 1024
#define MAXN 32
#define NHID 512
#define NHEAD 8
#define NLAY 6
#define MTOT (NB * MAXN)   // 32768 rows
#define ATT_SCALE 0.125f
#define LN_EPS 1e-5f

__device__ __forceinline__ float bf2f(u16 h) { return __uint_as_float(((u32)h) << 16); }
__device__ __forceinline__ u16 f2bf(float f) {
  u32 u = __float_as_uint(f);
  return (u16)((u + 0x7fffu + ((u >> 16) & 1u)) >> 16);
}

__device__ __forceinline__ void gload16(const void* g, void* l) {
  __builtin_amdgcn_global_load_lds((const __attribute__((address_space(1))) void*)g,
                                   (__attribute__((address_space(3))) void*)l, 16, 0, 0);
}

// ---------------------------------------------------------------------------
// DAG reachability mask: per (b,q) a 32-bit "allowed key" mask.
__global__ __launch_bounds__(256) void mask_k(const int* __restrict__ adj, u32* __restrict__ mask) {
  __shared__ u32 r[8][32];
  int tid = threadIdx.x;
  int g = tid >> 5, i = tid & 31;
  int b = blockIdx.x * 8 + g;
  const int* ab = adj + ((long)b * 32 + i) * 32;
  u32 m = 0;
  for (int j = i + 1; j < 32; ++j)
    if (ab[j]) m |= (1u << j);
  r[g][i] = m;
  __syncthreads();
  for (int it = 0; it < 5; ++it) {
    u32 cur = r[g][i];
    u32 acc = cur;
    #pragma unroll
    for (int j = 0; j < 32; ++j)
      if ((cur >> j) & 1u) acc |= r[g][j];
    __syncthreads();
    r[g][i] = acc;
    __syncthreads();
  }
  u32 am = 1u << i;
  #pragma unroll
  for (int k = 0; k < 32; ++k) am |= ((r[g][k] >> i) & 1u) << k;
  mask[b * 32 + i] = am;
}

// ---------------------------------------------------------------------------
// Embedding: x[:, :256] = relu(Wnode[type]+bnode); x[:, 256:] = Wpos[n]+bpos.
__global__ __launch_bounds__(256) void embed_k(const int* __restrict__ types,
    const float* __restrict__ Wpos, const float* __restrict__ bpos,
    const float* __restrict__ Wnode, const float* __restrict__ bnode,
    float* __restrict__ x, u16* __restrict__ xb) {
  int i = blockIdx.x * 256 + threadIdx.x;
  int row = i >> 7, c = (i & 127) * 4;
  int b = row >> 5, n = row & 31;
  float v[4];
  if (c < 256) {
    int tp = types[b * 32 + n];
    const float* w = &Wnode[tp * 256 + c];
    #pragma unroll
    for (int j = 0; j < 4; ++j) v[j] = fmaxf(w[j] + bnode[c + j], 0.f);
  } else {
    int cc = c - 256;
    const float* w = &Wpos[n * 256 + cc];
    #pragma unroll
    for (int j = 0; j < 4; ++j) v[j] = w[j] + bpos[cc + j];
  }
  long o = (long)row * NHID + c;
  *(float4*)&x[o] = make_float4(v[0], v[1], v[2], v[3]);
  ushort4 h; h.x = f2bf(v[0]); h.y = f2bf(v[1]); h.z = f2bf(v[2]); h.w = f2bf(v[3]);
  *(ushort4*)&xb[o] = h;
}

// ---------------------------------------------------------------------------
// Weight transpose + f32->bf16: W[l][k][n] -> Wt[l][n_off+n][k]
__global__ __launch_bounds__(256) void tconv_k(const float* __restrict__ W,
    u16* __restrict__ Wt, int n_off, int n_total) {
  __shared__ float tile[32][33];
  int l = blockIdx.z;
  int k0 = blockIdx.x * 32, n0 = blockIdx.y * 32;
  int tx = threadIdx.x & 31, ty = threadIdx.x >> 5;
  const float* src = W + (size_t)l * NHID * NHID;
  #pragma unroll
  for (int i = 0; i < 4; ++i)
    tile[ty + 8 * i][tx] = src[(size_t)(k0 + ty + 8 * i) * NHID + n0 + tx];
  __syncthreads();
  u16* dst = Wt + (size_t)l * n_total * NHID;
  #pragma unroll
  for (int i = 0; i < 4; ++i)
    dst[(size_t)(n_off + n0 + ty + 8 * i) * NHID + k0 + tx] = f2bf(tile[tx][ty + 8 * i]);
}

// ---------------------------------------------------------------------------
// bf16 MFMA GEMM, m97 structure: C[M][N] = A[M][K] * Bt[N][K]^T (+bias).
// EPI: 1 = bf16 out + bias; 2 = bf16 out + bias + relu
template <int EPI>
__global__ __launch_bounds__(256, 2) void gemm_bt(
    const u16* __restrict__ A, const u16* __restrict__ Bt,
    const float* __restrict__ bias0, const float* __restrict__ bias1,
    const float* __restrict__ bias2, u16* __restrict__ Cout, int N, int K) {
  __shared__ u16 As[128 * 32];
  __shared__ u16 Bs[128 * 32];
  const int tid = threadIdx.x;
  const int wave = tid >> 6, lane = tid & 63;
  const long m0 = (long)blockIdx.y * 128;
  const int n0 = blockIdx.x * 128;
  const int wr = wave >> 1, wc = wave & 1;
  const int srow = lane >> 2;
  const int skof = (lane & 3) * 8;
  const int fr = lane & 15;
  const int kq = lane >> 4;
  f32x4 acc[4][4] = {};

  for (int k0 = 0; k0 < K; k0 += 32) {
    #pragma unroll
    for (int i = 0; i < 2; ++i) {
      int c = 2 * wave + i;
      gload16(A + (m0 + 16 * c + srow) * (long)K + k0 + skof, &As[c * 512]);
      gload16(Bt + (long)(n0 + 16 * c + srow) * K + k0 + skof, &Bs[c * 512]);
    }
    __syncthreads();
    bf16x8 af[4], bfr[4];
    #pragma unroll
    for (int mi = 0; mi < 4; ++mi)
      af[mi] = *(const bf16x8*)&As[(wr * 64 + mi * 16 + fr) * 32 + kq * 8];
    #pragma unroll
    for (int ni = 0; ni < 4; ++ni)
      bfr[ni] = *(const bf16x8*)&Bs[(wc * 64 + ni * 16 + fr) * 32 + kq * 8];
    #pragma unroll
    for (int mi = 0; mi < 4; ++mi)
      #pragma unroll
      for (int ni = 0; ni < 4; ++ni)
        acc[mi][ni] = __builtin_amdgcn_mfma_f32_16x16x32_bf16(af[mi], bfr[ni], acc[mi][ni], 0, 0, 0);
    __syncthreads();
  }

  #pragma unroll
  for (int ni = 0; ni < 4; ++ni) {
    int n = n0 + wc * 64 + ni * 16 + fr;
    const float* bp = (n < 512) ? bias0 : ((n < 1024) ? bias1 : bias2);
    float bias = bp[n & 511];
    #pragma unroll
    for (int mi = 0; mi < 4; ++mi) {
      long r = m0 + wr * 64 + mi * 16 + kq * 4;
      #pragma unroll
      for (int j = 0; j < 4; ++j) {
        float v = acc[mi][ni][j] + bias;
        if (EPI == 2) v = fmaxf(v, 0.f);
        Cout[(r + j) * (long)N + n] = f2bf(v);
      }
    }
  }
}

// ---------------------------------------------------------------------------
// MFMA attention: 1 wave per (b,head), 4 waves/block.
// S^T = mfma(K, Q): lane holds S^T[k = mi*16+g*4+j][q = nj*16+r].
// Softmax per q-column: per-lane 8 values + shfl_xor over lane groups.
// P staged to padded LDS [q][k], PV = mfma(P, V) with V column fragments.
__global__ __launch_bounds__(256) void attn_k(const u16* __restrict__ qkv,
    const u32* __restrict__ mask, u16* __restrict__ o) {
  __shared__ u16 p_lds[4][32][40];
  int tid = threadIdx.x;
  int w = tid >> 6, lane = tid & 63;
  int idx = blockIdx.x * 4 + w;
  int b = idx >> 3, h = idx & 7;
  const u16* base = qkv + (long)b * 32 * 1536;
  int g = lane >> 4, r = lane & 15;

  // --- S^T = K · Q^T (contraction over d = 64, 2 k-steps) ---
  f32x4 s[2][2] = {};
  #pragma unroll
  for (int ks = 0; ks < 2; ++ks) {
    bf16x8 kf[2], qf[2];
    #pragma unroll
    for (int mi = 0; mi < 2; ++mi)
      kf[mi] = *(const bf16x8*)(base + (long)(mi * 16 + r) * 1536 + 512 + h * 64 + ks * 32 + g * 8);
    #pragma unroll
    for (int nj = 0; nj < 2; ++nj)
      qf[nj] = *(const bf16x8*)(base + (long)(nj * 16 + r) * 1536 + h * 64 + ks * 32 + g * 8);
    #pragma unroll
    for (int mi = 0; mi < 2; ++mi)
      #pragma unroll
      for (int nj = 0; nj < 2; ++nj)
        s[mi][nj] = __builtin_amdgcn_mfma_f32_16x16x32_bf16(kf[mi], qf[nj], s[mi][nj], 0, 0, 0);
  }

  // --- masked softmax over k for each query column q ---
  #pragma unroll
  for (int nj = 0; nj < 2; ++nj) {
    int q = nj * 16 + r;
    u32 mk = mask[b * 32 + q];
    float v[8];
    float mx = -1e30f;
    #pragma unroll
    for (int mi = 0; mi < 2; ++mi)
      #pragma unroll
      for (int j = 0; j < 4; ++j) {
        int k = mi * 16 + g * 4 + j;
        float val = ((mk >> k) & 1u) ? s[mi][nj][j] * ATT_SCALE : -1e30f;
        v[mi * 4 + j] = val;
        mx = fmaxf(mx, val);
      }
    mx = fmaxf(mx, __shfl_xor(mx, 16));
    mx = fmaxf(mx, __shfl_xor(mx, 32));
    float sum = 0.f;
    #pragma unroll
    for (int i = 0; i < 8; ++i) { v[i] = __expf(v[i] - mx); sum += v[i]; }
    sum += __shfl_xor(sum, 16);
    sum += __shfl_xor(sum, 32);
    float inv = 1.f / sum;
    #pragma unroll
    for (int mi = 0; mi < 2; ++mi) {
      ushort4 pk;
      pk.x = f2bf(v[mi * 4 + 0] * inv);
      pk.y = f2bf(v[mi * 4 + 1] * inv);
      pk.z = f2bf(v[mi * 4 + 2] * inv);
      pk.w = f2bf(v[mi * 4 + 3] * inv);
      *(ushort4*)&p_lds[w][q][mi * 16 + g * 4] = pk;   // row stride 80B (16B-aligned)
    }
  }
  __syncthreads();

  // --- O = P · V (K=32, one MFMA per tile pair) ---
  bf16x8 pa[2];
  #pragma unroll
  for (int mi = 0; mi < 2; ++mi)
    pa[mi] = *(const bf16x8*)&p_lds[w][mi * 16 + r][g * 8];
  f32x4 oacc[2][4] = {};
  #pragma unroll
  for (int nd = 0; nd < 4; ++nd) {
    bf16x8 vf;
    #pragma unroll
    for (int t = 0; t < 8; ++t)
      vf[t] = *(const short*)(base + (long)(g * 8 + t) * 1536 + 1024 + h * 64 + nd * 16 + r);
    #pragma unroll
    for (int mi = 0; mi < 2; ++mi)
      oacc[mi][nd] = __builtin_amdgcn_mfma_f32_16x16x32_bf16(pa[mi], vf, oacc[mi][nd], 0, 0, 0);
  }
  #pragma unroll
  for (int mi = 0; mi < 2; ++mi)
    #pragma unroll
    for (int j = 0; j < 4; ++j) {
      int q = mi * 16 + g * 4 + j;
      u16* og = o + ((long)b * 32 + q) * NHID + h * 64;
      #pragma unroll
      for (int nd = 0; nd < 4; ++nd)
        og[nd * 16 + r] = f2bf(oacc[mi][nd][j]);
    }
}

// ---------------------------------------------------------------------------
// Residual + LayerNorm: x = LN(x + t)*g + b; t is bf16; writes f32 master + bf16.
__global__ __launch_bounds__(256) void ln_k(float* xio, const u16* __restrict__ t,
    const float* __restrict__ g, const float* __restrict__ b, u16* __restrict__ xb) {
  __shared__ float ps[4], psq[4];
  int tid = threadIdx.x;
  int half = tid >> 7, lt = tid & 127;
  long row = (long)blockIdx.x * 2 + half;
  int c = lt * 4;
  long o = row * NHID + c;
  float4 xv = *(const float4*)&xio[o];
  ushort4 tv = *(const ushort4*)&t[o];
  float y[4] = {xv.x + bf2f(tv.x), xv.y + bf2f(tv.y), xv.z + bf2f(tv.z), xv.w + bf2f(tv.w)};
  float s = y[0] + y[1] + y[2] + y[3];
  float sq = y[0] * y[0] + y[1] * y[1] + y[2] * y[2] + y[3] * y[3];
  #pragma unroll
  for (int off = 32; off; off >>= 1) {
    s += __shfl_down(s, off);
    sq += __shfl_down(sq, off);
  }
  int wave = tid >> 6;
  if ((tid & 63) == 0) { ps[wave] = s; psq[wave] = sq; }
  __syncthreads();
  int w0 = half * 2;
  float S = ps[w0] + ps[w0 + 1], SQ = psq[w0] + psq[w0 + 1];
  float mean = S * (1.f / 512.f);
  float var = SQ * (1.f / 512.f) - mean * mean;
  float inv = rsqrtf(var + LN_EPS);
  float out[4];
  #pragma unroll
  for (int j = 0; j < 4; ++j) out[j] = (y[j] - mean) * inv * g[c + j] + b[c + j];
  *(float4*)&xio[o] = make_float4(out[0], out[1], out[2], out[3]);
  ushort4 hv; hv.x = f2bf(out[0]); hv.y = f2bf(out[1]); hv.z = f2bf(out[2]); hv.w = f2bf(out[3]);
  *(ushort4*)&xb[o] = hv;
}

// ---------------------------------------------------------------------------
// Final FC weight transpose: W[16384][64] f32 -> Wt[sel*64 + n][16384] bf16.
__global__ __launch_bounds__(256) void fcT_k(const float* __restrict__ W1,
    const float* __restrict__ W2, u16* __restrict__ Wt) {
  __shared__ float t[64][65];
  int sel = blockIdx.y;
  const float* W = sel ? W2 : W1;
  int k0 = blockIdx.x * 64;
  int tx = threadIdx.x & 63, ty = threadIdx.x >> 6;
  #pragma unroll
  for (int i = 0; i < 16; ++i)
    t[ty + 4 * i][tx] = W[(long)(k0 + ty + 4 * i) * 64 + tx];
  __syncthreads();
  #pragma unroll
  for (int i = 0; i < 16; ++i)
    Wt[(long)(sel * 64 + ty + 4 * i) * 16384 + k0 + tx] = f2bf(t[tx][ty + 4 * i]);
}

// ---------------------------------------------------------------------------
// Final FC GEMM, K-split: part[ks][1024][128] = A[m][ks-chunk] * Wt[n][ks-chunk]^T
__global__ __launch_bounds__(256, 2) void gemm_fc(const u16* __restrict__ A,
    const u16* __restrict__ Bt, float* __restrict__ part) {
  __shared__ u16 As[128 * 32];
  __shared__ u16 Bs[128 * 32];
  const int tid = threadIdx.x;
  const int wave = tid >> 6, lane = tid & 63;
  const int ks = blockIdx.x;               // 32 k-chunks of 512
  const long m0 = (long)blockIdx.y * 128;
  const int kbase = ks * 512;
  const int wr = wave >> 1, wc = wave & 1;
  const int srow = lane >> 2;
  const int skof = (lane & 3) * 8;
  const int fr = lane & 15;
  const int kq = lane >> 4;
  f32x4 acc[4][4] = {};
  for (int k0 = 0; k0 < 512; k0 += 32) {
    #pragma unroll
    for (int i = 0; i < 2; ++i) {
      int c = 2 * wave + i;
      gload16(A + (m0 + 16 * c + srow) * 16384L + kbase + k0 + skof, &As[c * 512]);
      gload16(Bt + (long)(16 * c + srow) * 16384L + kbase + k0 + skof, &Bs[c * 512]);
    }
    __syncthreads();
    bf16x8 af[4], bfr[4];
    #pragma unroll
    for (int mi = 0; mi < 4; ++mi)
      af[mi] = *(const bf16x8*)&As[(wr * 64 + mi * 16 + fr) * 32 + kq * 8];
    #pragma unroll
    for (int ni = 0; ni < 4; ++ni)
      bfr[ni] = *(const bf16x8*)&Bs[(wc * 64 + ni * 16 + fr) * 32 + kq * 8];
    #pragma unroll
    for (int mi = 0; mi < 4; ++mi)
      #pragma unroll
      for (int ni = 0; ni < 4; ++ni)
        acc[mi][ni] = __builtin_amdgcn_mfma_f32_16x16x32_bf16(af[mi], bfr[ni], acc[mi][ni], 0, 0, 0);
    __syncthreads();
  }
  #pragma unroll
  for (int ni = 0; ni < 4; ++ni) {
    int n = wc * 64 + ni * 16 + fr;
    #pragma unroll
    for (int mi = 0; mi < 4; ++mi) {
      long rr = m0 + wr * 64 + mi * 16 + kq * 4;
      #pragma unroll
      for (int j = 0; j < 4; ++j)
        part[((long)ks * 1024 + rr + j) * 128 + n] = acc[mi][ni][j];
    }
  }
}

__global__ __launch_bounds__(256) void fc_red_k(const float* __restrict__ part,
    const float* __restrict__ bfc1, const float* __restrict__ bfc2,
    float* __restrict__ out) {
  int idx = blockIdx.x * 256 + threadIdx.x;   // 0..131071
  int sel = idx >> 16;
  int rem = idx & 65535;
  int b = rem >> 6, z = rem & 63;
  float v = sel ? bfc2[z] : bfc1[z];
  #pragma unroll
  for (int ks = 0; ks < 32; ++ks)
    v += part[((long)ks * 1024 + b) * 128 + sel * 64 + z];
  out[idx] = v;
}

// ---------------------------------------------------------------------------
extern "C" void kernel_launch(void* const* d_in, const int* in_sizes, int n_in,
                              void* d_out, int out_size, void* d_ws, size_t ws_size,
                              hipStream_t stream) {
  const int* node_types = (const int*)d_in[0];
  const int* adj_bits = (const int*)d_in[1];
  const float* Wpos = (const float*)d_in[2];
  const float* bpos = (const float*)d_in[3];
  const float* Wnode = (const float*)d_in[4];
  const float* bnode = (const float*)d_in[5];
  const float* eWq = (const float*)d_in[6];
  const float* eWk = (const float*)d_in[7];
  const float* eWv = (const float*)d_in[8];
  const float* eWo = (const float*)d_in[9];
  const float* eW1 = (const float*)d_in[10];
  const float* eW2 = (const float*)d_in[11];
  const float* ebq = (const float*)d_in[12];
  const float* ebk = (const float*)d_in[13];
  const float* ebv = (const float*)d_in[14];
  const float* ebo = (const float*)d_in[15];
  const float* eb1 = (const float*)d_in[16];
  const float* eb2 = (const float*)d_in[17];
  const float* ln1g = (const float*)d_in[18];
  const float* ln1b = (const float*)d_in[19];
  const float* ln2g = (const float*)d_in[20];
  const float* ln2b = (const float*)d_in[21];
  const float* Wfc1 = (const float*)d_in[22];
  const float* bfc1 = (const float*)d_in[23];
  const float* Wfc2 = (const float*)d_in[24];
  const float* bfc2 = (const float*)d_in[25];

  char* ws = (char*)d_ws;
  size_t off = 0;
  auto carve = [&](size_t bytes) {
    void* p = ws + off;
    off += (bytes + 255) & ~(size_t)255;
    return p;
  };
  u16* Wqkv_t = (u16*)carve((size_t)NLAY * 1536 * 512 * 2);
  u16* Wo_t = (u16*)carve((size_t)NLAY * 512 * 512 * 2);
  u16* W1_t = (u16*)carve((size_t)NLAY * 512 * 512 * 2);
  u16* W2_t = (u16*)carve((size_t)NLAY * 512 * 512 * 2);
  float* xf = (float*)carve((size_t)MTOT * NHID * 4);
  u16* xb = (u16*)carve((size_t)MTOT * NHID * 2);
  u16* qkv = (u16*)carve((size_t)MTOT * 1536 * 2);   // reused: tmp16, Wt_fc
  u16* obuf = (u16*)carve((size_t)MTOT * NHID * 2);  // reused: hbuf, fc partials
  u32* maskb = (u32*)carve((size_t)NB * MAXN * 4);
  u16* tmp16 = qkv;          // layer MLP/O-proj outputs (dead QKV region)
  u16* hbuf = obuf;
  u16* Wt_fc = qkv;          // FC-time alias (qkv/tmp16 dead by then): 4 MB
  float* part_fc = (float*)obuf;  // FC-time alias: 32*1024*128*4 = 16.8 MB

  // --- prep ---
  mask_k<<<NB / 8, 256, 0, stream>>>(adj_bits, maskb);
  embed_k<<<(MTOT * 128) / 256, 256, 0, stream>>>(node_types, Wpos, bpos, Wnode, bnode, xf, xb);
  dim3 tg(16, 16, NLAY);
  tconv_k<<<tg, 256, 0, stream>>>(eWq, Wqkv_t, 0, 1536);
  tconv_k<<<tg, 256, 0, stream>>>(eWk, Wqkv_t, 512, 1536);
  tconv_k<<<tg, 256, 0, stream>>>(eWv, Wqkv_t, 1024, 1536);
  tconv_k<<<tg, 256, 0, stream>>>(eWo, Wo_t, 0, 512);
  tconv_k<<<tg, 256, 0, stream>>>(eW1, W1_t, 0, 512);
  tconv_k<<<tg, 256, 0, stream>>>(eW2, W2_t, 0, 512);

  // --- encoder layers ---
  for (int l = 0; l < NLAY; ++l) {
    size_t lw = (size_t)l * 512 * 512;
    gemm_bt<1><<<dim3(12, MTOT / 128), 256, 0, stream>>>(
        xb, Wqkv_t + (size_t)l * 1536 * 512,
        ebq + l * 512, ebk + l * 512, ebv + l * 512, qkv, 1536, 512);
    attn_k<<<NB * NHEAD / 4, 256, 0, stream>>>(qkv, maskb, obuf);
    gemm_bt<1><<<dim3(4, MTOT / 128), 256, 0, stream>>>(
        obuf, Wo_t + lw, ebo + l * 512, ebo + l * 512, ebo + l * 512, tmp16, 512, 512);
    ln_k<<<MTOT / 2, 256, 0, stream>>>(xf, tmp16, ln1g + l * 512, ln1b + l * 512, xb);
    gemm_bt<2><<<dim3(4, MTOT / 128), 256, 0, stream>>>(
        xb, W1_t + lw, eb1 + l * 512, eb1 + l * 512, eb1 + l * 512, hbuf, 512, 512);
    gemm_bt<1><<<dim3(4, MTOT / 128), 256, 0, stream>>>(
        hbuf, W2_t + lw, eb2 + l * 512, eb2 + l * 512, eb2 + l * 512, tmp16, 512, 512);
    ln_k<<<MTOT / 2, 256, 0, stream>>>(xf, tmp16, ln2g + l * 512, ln2b + l * 512, xb);
  }

  // --- final FC: transpose weights (into dead qkv region), K-split MFMA, reduce ---
  fcT_k<<<dim3(256, 2), 256, 0, stream>>>(Wfc1, Wfc2, Wt_fc);
  gemm_fc<<<dim3(32, 8), 256, 0, stream>>>(xb, Wt_fc, part_fc);
  fc_red_k<<<512, 256, 0, stream>>>(part_fc, bfc1, bfc2, (float*)d_out);
}